// Round 6
// baseline (193.817 us; speedup 1.0000x reference)
//
#include <hip/hip_runtime.h>

// SpatialAttention fp32: B=128, C=3, H=W=256, 8x8 patches, FEAT=192, ENC=16.
// R10: cut VALU ops at constant occupancy. R9 proved weight-delivery stalls
// gone (VALUBusy 35->62%) but readlane doubled per-FMA cost; dur ~= VALU
// issue (45us) + stalls (28us). VGPR-vs-occupancy reconciliation across
// R4-R9: phys VGPR >64 halves waves/CU -> multi-patch amortization is dead.
// Two cuts instead, same R9 skeleton (8 waves x 24 feat, 1 patch/lane):
//  1) Decoder weights -> s_load SGPR pairs (scalar pipe now UNCONTENDED:
//     working set = Wdec+biases ~13KB <= 16KB sK$; R6's thrash needed 25KB).
//     e-pair float2 dot: a2.x=fmaf(w2.x,h2.x,a2.x); a2.y=... -> SLP can form
//     v_pk_fma_f32 (fp32 peak 157TF = 2x plain fma rate requires it).
//     Decoder: 384 fma + 384 rdl -> 192 pk + 24 adds, zero readlanes.
//  2) Encoder: float2 accumulator over q-pairs: two independent fma chains
//     per e (hides 4cy dep latency) + pk-pairable readlane pairs.
// hl staged as float2[8][64]: reduce-dedup wave wv owns exactly e={2wv,2wv+1}
// -> single b64 store; decoder picks up h2[8] pairs.
// Tripwires: VGPR reported <=32 (phys 64, 8 waves/SIMD), WRITE ~98.3MB.

constexpr int NPATCH = 128 * 32 * 32;
constexpr float L2E  = 1.4426950408889634f;

__device__ __forceinline__ float rdlane(float v, int l) {
  return __uint_as_float(__builtin_amdgcn_readlane(__float_as_uint(v), l));
}

__global__ __launch_bounds__(512, 4) void spatial_attn(
    const float* __restrict__ x,      // [128][3][256][256]
    const float* __restrict__ Wenc,   // [16][192]
    const float* __restrict__ benc,   // [16]
    const float* __restrict__ Wdec,   // [192][16]
    const float* __restrict__ bdec,   // [192]
    float* __restrict__ y)            // [128][3][256][256]
{
  __shared__ float  encl[16 * 512];   // [e][tid] encoder partials (32 KB)
  __shared__ float2 hl2[8 * 64];      // [e-pair][patch-lane] relu'd h (4 KB)
  __shared__ float  sls[512];         // softmax partials (2 KB)

  const int tid  = threadIdx.x;
  const int lane = tid & 63;
  const int wv   = __builtin_amdgcn_readfirstlane(tid >> 6);  // uniform
  const int p    = blockIdx.x * 64 + lane;                    // one patch/lane
  const int b    = p >> 10;
  const int ii   = (p >> 5) & 31;
  const int jj   = p & 31;
  const size_t base = (size_t)b * 196608 + (size_t)ii * 2048 + (size_t)jj * 8;

  // ---- Preload this wave's Wenc slice into VGPRs (per-lane VMEM, once) ----
  float we[16];                       // Wenc[e][wv*24 + col], col = lane<24
  const int col = (lane < 24) ? lane : 0;   // clamp: junk lanes unused
  #pragma unroll
  for (int e = 0; e < 16; ++e) we[e] = Wenc[e * 192 + wv * 24 + col];

  // ---- Load this wave's 24 features (rows 3wv..3wv+2), coalesced float4 ----
  float2 xv2[12];
  #pragma unroll
  for (int t = 0; t < 3; ++t) {
    const int cr = 3 * wv + t;
    const float* src = x + base + (cr >> 3) * 65536 + (cr & 7) * 256;
    const float4 v0 = *(const float4*)(src);
    const float4 v1 = *(const float4*)(src + 4);
    xv2[t*4+0] = make_float2(v0.x, v0.y);
    xv2[t*4+1] = make_float2(v0.z, v0.w);
    xv2[t*4+2] = make_float2(v1.x, v1.y);
    xv2[t*4+3] = make_float2(v1.z, v1.w);
  }

  // ---- Encoder: two independent fma chains per e (pk-pairable) ----
  #pragma unroll
  for (int e = 0; e < 16; ++e) {
    float2 a2 = make_float2(0.0f, 0.0f);
    #pragma unroll
    for (int k = 0; k < 12; ++k) {
      a2.x = fmaf(rdlane(we[e], 2 * k),     xv2[k].x, a2.x);
      a2.y = fmaf(rdlane(we[e], 2 * k + 1), xv2[k].y, a2.y);
    }
    encl[e * 512 + tid] = a2.x + a2.y;  // one acc pair live at a time
  }
  __syncthreads();

  // ---- Cross-wave reduce, de-dup: wave wv owns e-pair {2wv, 2wv+1} ----
  {
    const int e0 = 2 * wv;
    const float* c0 = encl + e0 * 512 + lane;
    const float* c1 = c0 + 512;
    float a0 = c0[0], a1 = c1[0];
    #pragma unroll
    for (int w8 = 1; w8 < 8; ++w8) { a0 += c0[w8 * 64]; a1 += c1[w8 * 64]; }
    hl2[wv * 64 + lane] = make_float2(fmaxf(a0 + benc[e0],     0.0f),
                                      fmaxf(a1 + benc[e0 + 1], 0.0f));
  }
  __syncthreads();

  // ---- All waves pick up h as 8 float2 pairs (b64, ~conflict-free) ----
  float2 h2[8];
  #pragma unroll
  for (int k = 0; k < 8; ++k) h2[k] = hl2[k * 64 + lane];

  // ---- Decoder: e-pair dot, weights via s_load pairs (sK$-hot, 13KB) ----
  float o[24];
  float s = 0.0f;
  #pragma unroll
  for (int q = 0; q < 24; ++q) {
    const int f = wv * 24 + q;
    const float2* w2 = (const float2*)(Wdec + f * 16);  // wave-uniform
    float2 a2 = make_float2(bdec[f], 0.0f);
    #pragma unroll
    for (int k = 0; k < 8; ++k) {
      a2.x = fmaf(w2[k].x, h2[k].x, a2.x);
      a2.y = fmaf(w2[k].y, h2[k].y, a2.y);
    }
    float v = fmaxf(a2.x + a2.y, 0.0f);
    o[q] = v;
    s += __builtin_amdgcn_exp2f(v * L2E);   // out>=0, bounded: no max-sub
  }

  // ---- Softmax denominator across the 8 waves ----
  sls[tid] = s;
  __syncthreads();
  float st = sls[lane];
  #pragma unroll
  for (int w8 = 1; w8 < 8; ++w8) st += sls[w8 * 64 + lane];
  const float inv = __builtin_amdgcn_rcpf(st);

  // ---- y = softmax(out)*out, coalesced float4 stores ----
  #pragma unroll
  for (int t = 0; t < 3; ++t) {
    const int cr = 3 * wv + t;
    float* dst = y + base + (cr >> 3) * 65536 + (cr & 7) * 256;
    float r[8];
    #pragma unroll
    for (int c = 0; c < 8; ++c) {
      const float ov = o[t * 8 + c];
      r[c] = __builtin_amdgcn_exp2f(ov * L2E) * inv * ov;
    }
    const float4 s0 = {r[0], r[1], r[2], r[3]};
    const float4 s1 = {r[4], r[5], r[6], r[7]};
    *(float4*)(dst)     = s0;
    *(float4*)(dst + 4) = s1;
  }
}

extern "C" void kernel_launch(void* const* d_in, const int* in_sizes, int n_in,
                              void* d_out, int out_size, void* d_ws, size_t ws_size,
                              hipStream_t stream) {
  const float* x    = (const float*)d_in[0];
  const float* Wenc = (const float*)d_in[1];
  const float* benc = (const float*)d_in[2];
  const float* Wdec = (const float*)d_in[3];
  const float* bdec = (const float*)d_in[4];
  float* y = (float*)d_out;
  dim3 grid(NPATCH / 64), block(512);
  hipLaunchKernelGGL(spatial_attn, grid, block, 0, stream, x, Wenc, benc, Wdec, bdec, y);
}